// Round 6
// baseline (285.338 us; speedup 1.0000x reference)
//
#include <hip/hip_runtime.h>
#include <math.h>

#define B_    32
#define C_    384
#define RHO_  25
#define WP_   256
#define PIX_  4096
#define D_    768
#define HID_  40
#define NROWS (B_*C_*RHO_)     // 307200
#define PCHUNK 4               // p-dimension split for cart GEMM
#define FE_N (RHO_*B_*D_)      // 614400
#define MAINBLK (B_*6*PCHUNK)  // 768
#define PROWS_PER_BLK 400      // 307200/768

__device__ __forceinline__ float gelu_exact(float x) {
    return 0.5f * x * (1.f + erff(x * 0.70710678118654752f));
}

// async global->LDS DMA, 16B per lane, dest = wave-uniform base + lane*16
__device__ __forceinline__ void gl_lds16(const float* g, float* l) {
    __builtin_amdgcn_global_load_lds((const __attribute__((address_space(1))) void*)g,
                                     (__attribute__((address_space(3))) void*)l, 16, 0, 0);
}

// ---------------- K1: bins via LDS atomics + W1 transpose + fe zero ----------------
__global__ __launch_bounds__(256) void prep_kernel(const float* __restrict__ grid,
        const float* __restrict__ W1_0, const float* __restrict__ W1s,
        float* __restrict__ bins, float* __restrict__ W1T, float* __restrict__ fe) {
    __shared__ float lb[PIX_];
    int tid = threadIdx.x;
    if (blockIdx.x < B_ * RHO_) {
        for (int i = tid; i < PIX_ / 4; i += 256) ((float4*)lb)[i] = make_float4(0.f, 0.f, 0.f, 0.f);
        __syncthreads();
        int pt = blockIdx.x * WP_ + tid;                 // (b,rho) block owns its 256 points
        float2 g = ((const float2*)grid)[pt];
        float ix = (g.x + 1.f) * 32.f - 0.5f;
        float iy = (g.y + 1.f) * 32.f - 0.5f;
        float x0f = floorf(ix), y0f = floorf(iy);
        float fx = ix - x0f, fy = iy - y0f;
        int x0 = (int)x0f, y0 = (int)y0f;
        const float s = 1.f / 256.f;
        if ((unsigned)x0 < 64u) {
            if ((unsigned)y0 < 64u)       atomicAdd(&lb[y0 * 64 + x0],       (1.f - fx) * (1.f - fy) * s);
            if ((unsigned)(y0 + 1) < 64u) atomicAdd(&lb[(y0 + 1) * 64 + x0], (1.f - fx) * fy * s);
        }
        if ((unsigned)(x0 + 1) < 64u) {
            if ((unsigned)y0 < 64u)       atomicAdd(&lb[y0 * 64 + x0 + 1],       fx * (1.f - fy) * s);
            if ((unsigned)(y0 + 1) < 64u) atomicAdd(&lb[(y0 + 1) * 64 + x0 + 1], fx * fy * s);
        }
        __syncthreads();
        float4* dst = (float4*)(bins + (size_t)blockIdx.x * PIX_);
        for (int i = tid; i < PIX_ / 4; i += 256) dst[i] = ((float4*)lb)[i];
    } else if (blockIdx.x < B_ * RHO_ + 25) {
        int i = blockIdx.x - B_ * RHO_;                  // head 0..24
        const float* src = (i == 0) ? W1_0 : (W1s + (size_t)(i - 1) * 769 * HID_);
        float* dst = W1T + (size_t)i * HID_ * D_;
        for (int idx = tid; idx < HID_ * D_; idx += 256) {
            int j = idx / D_, c = idx % D_;
            dst[idx] = src[c * HID_ + j];
        }
    } else {
        int z = blockIdx.x - (B_ * RHO_ + 25);           // 0..49, zero fe (cart half accumulated)
        float4* f4 = (float4*)fe;
        int per = FE_N / 4 / 50;                         // 3072 float4 per block
        for (int i = tid; i < per; i += 256)
            f4[z * per + i] = make_float4(0.f, 0.f, 0.f, 0.f);
    }
}

// ---------------- K2: fused main — cart GEMM (counted-vmcnt dbuf) + interleaved polar mean ----------
// block = (b, 64-ch tile, p-chunk of 1024): 16 tiles of 64 p, double-buffered via async DMA.
// Per tile each wave: 6 polar row loads (oldest) + 6 stage loads; s_waitcnt vmcnt(12) keeps
// next-tile stage in flight across the raw barrier. Each block also owns 400 polar rows.
__global__ __launch_bounds__(256) void main_kernel(const float* __restrict__ polar,
        const float* __restrict__ cart, const float* __restrict__ bins,
        float* __restrict__ fe) {
    __shared__ float smem[12288];                        // 2 x (4096 X + 2048 W) floats = 48 KB
    const int BUF = 6144;
    int bid = blockIdx.x;
    int b  = bid / (6 * PCHUNK);
    int ct = (bid / PCHUNK) % 6;
    int pc = bid % PCHUNK;
    int c0 = ct * 64;
    int tid = threadIdx.x;
    int lane = tid & 63, w = tid >> 6, h = lane >> 4;    // h in 0..3
    int c = tid & 15, q = tid >> 4;                      // q in 0..15 (p-quad)
    const float* binb  = bins + (size_t)b * RHO_ * PIX_ + pc * 1024;
    const float* cartb = cart + ((size_t)b * C_ + c0) * PIX_ + pc * 1024;
    int rbase = bid * PROWS_PER_BLK;

    // per-lane global sources (source-swizzled X, linear W); per-wave LDS unit offsets
    const float* gX[4]; int uXo[4];
    #pragma unroll
    for (int k = 0; k < 4; ++k) {
        int u = w + 4 * k;                               // X unit 0..15, rows 4u..4u+3
        int row = 4 * u + h;
        gX[k] = cartb + (size_t)row * PIX_ + (((lane & 15) ^ (row & 15)) << 2);
        uXo[k] = u << 8;
    }
    const float* gW[2]; int uWo[2];
    #pragma unroll
    for (int k = 0; k < 2; ++k) {
        int u = w + 4 * k;                               // W unit 0..7 (rows 25..31 junk from pad)
        gW[k] = binb + (size_t)(4 * u + h) * PIX_ + ((lane & 15) << 2);
        uWo[k] = 4096 + (u << 8);
    }

    float acc[4][25];
    #pragma unroll
    for (int jj = 0; jj < 4; ++jj)
        #pragma unroll
        for (int r = 0; r < 25; ++r) acc[jj][r] = 0.f;

    // prologue: stage tile 0 into buffer 0 (6 loads/wave in flight)
    #pragma unroll
    for (int k = 0; k < 4; ++k) gl_lds16(gX[k], smem + uXo[k]);
    #pragma unroll
    for (int k = 0; k < 2; ++k) gl_lds16(gW[k], smem + uWo[k]);

    for (int t = 0; t < 16; ++t) {
        int cbase = (t & 1) * BUF;
        int nbase = cbase ^ BUF;
        // 1. polar row loads (issued first -> oldest in vmcnt FIFO)
        int prow = rbase + t * 24 + w * 6;
        float4 pv[6];
        #pragma unroll
        for (int j = 0; j < 6; ++j)
            pv[j] = ((const float4*)(polar + (size_t)(prow + j) * WP_))[lane];
        // 2. async stage of tile t+1
        if (t < 15) {
            int p0 = (t + 1) << 6;
            #pragma unroll
            for (int k = 0; k < 4; ++k) gl_lds16(gX[k] + p0, smem + nbase + uXo[k]);
            #pragma unroll
            for (int k = 0; k < 2; ++k) gl_lds16(gW[k] + p0, smem + nbase + uWo[k]);
            asm volatile("s_waitcnt vmcnt(12)" ::: "memory");   // tile-t stage landed; 12 newer stay
        } else {
            asm volatile("s_waitcnt vmcnt(6)" ::: "memory");    // drain last stage; polar stays
        }
        __builtin_amdgcn_s_barrier();
        // 3. GEMM compute on current buffer
        const float* Xb = smem + cbase;
        const float* Wb = smem + cbase + 4096;
        int sx = (q ^ c) << 2;                           // un-swizzle on read (~2-way banks, free)
        float4 x0 = *(const float4*)(Xb + ((c     ) << 6) + sx);
        float4 x1 = *(const float4*)(Xb + ((c + 16) << 6) + sx);
        float4 x2 = *(const float4*)(Xb + ((c + 32) << 6) + sx);
        float4 x3 = *(const float4*)(Xb + ((c + 48) << 6) + sx);
        #pragma unroll
        for (int r = 0; r < 25; ++r) {
            float4 wv = *(const float4*)(Wb + (r << 6) + (q << 2));   // 4 addrs/wave -> broadcast
            acc[0][r] += x0.x * wv.x + x0.y * wv.y + x0.z * wv.z + x0.w * wv.w;
            acc[1][r] += x1.x * wv.x + x1.y * wv.y + x1.z * wv.z + x1.w * wv.w;
            acc[2][r] += x2.x * wv.x + x2.y * wv.y + x2.z * wv.z + x2.w * wv.w;
            acc[3][r] += x3.x * wv.x + x3.y * wv.y + x3.z * wv.z + x3.w * wv.w;
        }
        // 4. polar reduce (consumes pv; compiler waits only past stage loads)
        #pragma unroll
        for (int j = 0; j < 6; ++j) {
            float s = pv[j].x + pv[j].y + pv[j].z + pv[j].w;
            #pragma unroll
            for (int m = 32; m >= 1; m >>= 1) s += __shfl_xor(s, m, 64);
            if (lane == 0) {
                int r = prow + j;
                int rho = r % RHO_, cch = (r / RHO_) % C_, bb = r / (RHO_ * C_);
                fe[((size_t)(rho * B_ + bb)) * D_ + cch] = s * (1.f / 256.f);
            }
        }
        __builtin_amdgcn_s_barrier();                    // compute(t) done before anyone stages into cbase
    }

    // leftover polar rows (16 per block, 4 per wave)
    int prow2 = rbase + 384 + w * 4;
    float4 qv[4];
    #pragma unroll
    for (int j = 0; j < 4; ++j)
        qv[j] = ((const float4*)(polar + (size_t)(prow2 + j) * WP_))[lane];

    // fold h-groups within wave (q = 4w+h): shfl 16,32 sum over h
    #pragma unroll
    for (int jj = 0; jj < 4; ++jj)
        #pragma unroll
        for (int r = 0; r < 25; ++r) {
            acc[jj][r] += __shfl_xor(acc[jj][r], 16, 64);
            acc[jj][r] += __shfl_xor(acc[jj][r], 32, 64);
        }

    #pragma unroll
    for (int j = 0; j < 4; ++j) {
        float s = qv[j].x + qv[j].y + qv[j].z + qv[j].w;
        #pragma unroll
        for (int m = 32; m >= 1; m >>= 1) s += __shfl_xor(s, m, 64);
        if (lane == 0) {
            int r = prow2 + j;
            int rho = r % RHO_, cch = (r / RHO_) % C_, bb = r / (RHO_ * C_);
            fe[((size_t)(rho * B_ + bb)) * D_ + cch] = s * (1.f / 256.f);
        }
    }

    if (lane < 16) {                                     // h==0 lanes hold wave partials
        #pragma unroll
        for (int jj = 0; jj < 4; ++jj)
            #pragma unroll
            for (int r = 0; r < 25; ++r)
                smem[((w * 4 + jj) * 16 + c) * 25 + r] = acc[jj][r];
    }
    __syncthreads();
    for (int oi = tid; oi < 1600; oi += 256) {
        int cc = oi / 25, r = oi % 25;
        int jj = cc >> 4, cl = cc & 15;
        float ssum = 0.f;
        #pragma unroll
        for (int ww = 0; ww < 4; ++ww)
            ssum += smem[((ww * 4 + jj) * 16 + cl) * 25 + r];
        atomicAdd(&fe[((size_t)(r * B_ + b)) * D_ + 384 + c0 + cc], ssum);
    }
}

// ---------------- K3: G[i][b][j] = fe[i][b][:] @ W1 + b1 ; wave per (i,b,j-half) ----------------
__global__ __launch_bounds__(256) void mlp_pre_kernel(const float* __restrict__ fe,
        const float* __restrict__ W1T, const float* __restrict__ b1_0,
        const float* __restrict__ b1s, float* __restrict__ G) {
    int lane = threadIdx.x & 63;
    int trip = blockIdx.x * 4 + (threadIdx.x >> 6);      // 0..1599 = (i,b,jh)
    int jh = trip & 1;
    int pair = trip >> 1;
    int i = pair >> 5, b = pair & 31;
    const float4* f4p = (const float4*)(fe + (size_t)(i * B_ + b) * D_);
    float4 f0 = f4p[lane], f1 = f4p[lane + 64], f2 = f4p[lane + 128];
    int j0 = jh * 20;
    #pragma unroll 2
    for (int j = j0; j < j0 + 20; ++j) {
        const float4* w4p = (const float4*)(W1T + ((size_t)i * HID_ + j) * D_);
        float4 w0 = w4p[lane], w1 = w4p[lane + 64], w2 = w4p[lane + 128];
        float s = f0.x*w0.x + f0.y*w0.y + f0.z*w0.z + f0.w*w0.w
                + f1.x*w1.x + f1.y*w1.y + f1.z*w1.z + f1.w*w1.w
                + f2.x*w2.x + f2.y*w2.y + f2.z*w2.z + f2.w*w2.w;
        #pragma unroll
        for (int m = 32; m >= 1; m >>= 1) s += __shfl_xor(s, m, 64);
        if (lane == 0) {
            float bias = (i == 0) ? b1_0[j] : b1s[(i - 1) * HID_ + j];
            G[(size_t)(i * B_ + b) * HID_ + j] = s + bias;
        }
    }
}

// ---------------- K4: sequential heads, register-resident, wave-synchronous ----------------
__global__ __launch_bounds__(64) void mlp_seq_kernel(const float* __restrict__ G,
        const float* __restrict__ W1s, const float* __restrict__ W2_0,
        const float* __restrict__ b2_0, const float* __restrict__ W2s,
        const float* __restrict__ b2s, float* __restrict__ out) {
    int lane = threadIdx.x;
    int j2 = lane & 31, b = blockIdx.x * 2 + (lane >> 5);
    bool hi = (j2 < 8);
    float g1[25], g2[25], wl1[25], wl2[25], w2a[25], w2b[25], bsc[25];
    #pragma unroll
    for (int i = 0; i < 25; ++i) {
        g1[i] = G[(size_t)(i * B_ + b) * HID_ + j2];
        g2[i] = hi ? G[(size_t)(i * B_ + b) * HID_ + 32 + j2] : 0.f;
    }
    wl1[0] = 0.f; wl2[0] = 0.f;
    w2a[0] = W2_0[j2]; w2b[0] = hi ? W2_0[32 + j2] : 0.f; bsc[0] = b2_0[0];
    #pragma unroll
    for (int i = 1; i < 25; ++i) {
        size_t base = ((size_t)(i - 1) * 769 + 768) * HID_;   // recurrent row of W1
        wl1[i] = W1s[base + j2];
        wl2[i] = hi ? W1s[base + 32 + j2] : 0.f;
        w2a[i] = W2s[(i - 1) * HID_ + j2];
        w2b[i] = hi ? W2s[(i - 1) * HID_ + 32 + j2] : 0.f;
        bsc[i] = b2s[i - 1];
    }
    float op = 0.f;
    #pragma unroll
    for (int i = 0; i < 25; ++i) {
        float x1 = g1[i] + op * wl1[i];
        float x2 = g2[i] + op * wl2[i];
        float p = gelu_exact(x1) * w2a[i] + gelu_exact(x2) * w2b[i];
        #pragma unroll
        for (int m = 16; m >= 1; m >>= 1) p += __shfl_xor(p, m, 64);   // stays within 32-lane group
        float o = p + bsc[i];
        op = o;
        if (j2 == 0) out[b * 25 + i] = fminf(fmaxf(o, 0.f), 3.14159265358979323846f);
    }
}

extern "C" void kernel_launch(void* const* d_in, const int* in_sizes, int n_in,
                              void* d_out, int out_size, void* d_ws, size_t ws_size,
                              hipStream_t stream) {
    const float* polar = (const float*)d_in[0];
    const float* cart  = (const float*)d_in[1];
    const float* grid  = (const float*)d_in[2];
    const float* W1_0  = (const float*)d_in[3];
    const float* b1_0  = (const float*)d_in[4];
    const float* W2_0  = (const float*)d_in[5];
    const float* b2_0  = (const float*)d_in[6];
    const float* W1s   = (const float*)d_in[7];
    const float* b1s   = (const float*)d_in[8];
    const float* W2s   = (const float*)d_in[9];
    const float* b2s   = (const float*)d_in[10];
    float* out = (float*)d_out;

    // ws layout (floats): bins[800*4096 + 8*4096 pad (junk W rows 25..31)] | fe | G | W1T
    float* bins = (float*)d_ws;
    float* fe   = bins + (size_t)(B_ * RHO_ + 8) * PIX_;
    float* G    = fe + (size_t)FE_N;
    float* W1T  = G + (size_t)RHO_ * B_ * HID_;

    prep_kernel<<<B_ * RHO_ + 25 + 50, 256, 0, stream>>>(grid, W1_0, W1s, bins, W1T, fe);
    main_kernel<<<MAINBLK, 256, 0, stream>>>(polar, cart, bins, fe);
    mlp_pre_kernel<<<(RHO_ * B_ * 2) / 4, 256, 0, stream>>>(fe, W1T, b1_0, b1s, G);
    mlp_seq_kernel<<<B_ / 2, 64, 0, stream>>>(G, W1s, W2_0, b2_0, W2s, b2s, out);
}

// Round 7
// 213.696 us; speedup vs baseline: 1.3353x; 1.3353x over previous
//
#include <hip/hip_runtime.h>
#include <math.h>

#define B_    32
#define C_    384
#define RHO_  25
#define WP_   256
#define PIX_  4096
#define D_    768
#define HID_  40
#define NROWS (B_*C_*RHO_)     // 307200
#define PCHUNK 4               // p-dimension split for cart GEMM
#define FE_N (RHO_*B_*D_)      // 614400
#define CARTBLK 768
#define MAINBLK 1536           // even bid -> cart, odd bid -> polar
#define PNW (768*4)            // polar waves = 3072

__device__ __forceinline__ float gelu_exact(float x) {
    return 0.5f * x * (1.f + erff(x * 0.70710678118654752f));
}

// async global->LDS DMA, 16B per lane, dest = wave-uniform base + lane*16
__device__ __forceinline__ void gl_lds16(const float* g, float* l) {
    __builtin_amdgcn_global_load_lds((const __attribute__((address_space(1))) void*)g,
                                     (__attribute__((address_space(3))) void*)l, 16, 0, 0);
}

// ---------------- K1: bins via LDS atomics + W1 transpose + fe zero ----------------
__global__ __launch_bounds__(256) void prep_kernel(const float* __restrict__ grid,
        const float* __restrict__ W1_0, const float* __restrict__ W1s,
        float* __restrict__ bins, float* __restrict__ W1T, float* __restrict__ fe) {
    __shared__ float lb[PIX_];
    int tid = threadIdx.x;
    if (blockIdx.x < B_ * RHO_) {
        for (int i = tid; i < PIX_ / 4; i += 256) ((float4*)lb)[i] = make_float4(0.f, 0.f, 0.f, 0.f);
        __syncthreads();
        int pt = blockIdx.x * WP_ + tid;                 // (b,rho) block owns its 256 points
        float2 g = ((const float2*)grid)[pt];
        float ix = (g.x + 1.f) * 32.f - 0.5f;
        float iy = (g.y + 1.f) * 32.f - 0.5f;
        float x0f = floorf(ix), y0f = floorf(iy);
        float fx = ix - x0f, fy = iy - y0f;
        int x0 = (int)x0f, y0 = (int)y0f;
        const float s = 1.f / 256.f;
        if ((unsigned)x0 < 64u) {
            if ((unsigned)y0 < 64u)       atomicAdd(&lb[y0 * 64 + x0],       (1.f - fx) * (1.f - fy) * s);
            if ((unsigned)(y0 + 1) < 64u) atomicAdd(&lb[(y0 + 1) * 64 + x0], (1.f - fx) * fy * s);
        }
        if ((unsigned)(x0 + 1) < 64u) {
            if ((unsigned)y0 < 64u)       atomicAdd(&lb[y0 * 64 + x0 + 1],       fx * (1.f - fy) * s);
            if ((unsigned)(y0 + 1) < 64u) atomicAdd(&lb[(y0 + 1) * 64 + x0 + 1], fx * fy * s);
        }
        __syncthreads();
        float4* dst = (float4*)(bins + (size_t)blockIdx.x * PIX_);
        for (int i = tid; i < PIX_ / 4; i += 256) dst[i] = ((float4*)lb)[i];
    } else if (blockIdx.x < B_ * RHO_ + 25) {
        int i = blockIdx.x - B_ * RHO_;                  // head 0..24
        const float* src = (i == 0) ? W1_0 : (W1s + (size_t)(i - 1) * 769 * HID_);
        float* dst = W1T + (size_t)i * HID_ * D_;
        for (int idx = tid; idx < HID_ * D_; idx += 256) {
            int j = idx / D_, c = idx % D_;
            dst[idx] = src[c * HID_ + j];
        }
    } else {
        int z = blockIdx.x - (B_ * RHO_ + 25);           // 0..49, zero fe (cart half accumulated)
        float4* f4 = (float4*)fe;
        int per = FE_N / 4 / 50;                         // 3072 float4 per block
        for (int i = tid; i < per; i += 256)
            f4[z * per + i] = make_float4(0.f, 0.f, 0.f, 0.f);
    }
}

// ---------------- K2: main — role-interleaved cart GEMM (counted vmcnt) / polar mean ----------
// Even blocks: cart GEMM, double-buffered async DMA, s_waitcnt vmcnt(6) keeps next-tile
// loads in flight across raw barriers. Odd blocks: polar width-mean (same resource shape,
// so 3 blocks/CU mix; polar waves fill cart's memory-wait cycles).
__global__ __launch_bounds__(256) void main_kernel(const float* __restrict__ polar,
        const float* __restrict__ cart, const float* __restrict__ bins,
        float* __restrict__ fe) {
    __shared__ float smem[12288];                        // 2 x (4096 X + 2048 W) floats = 48 KB
    const int BUF = 6144;
    int tid = threadIdx.x;
    int lane = tid & 63, w = tid >> 6;

    if ((blockIdx.x & 1) == 0) {
        // -------- cart role --------
        int idx = blockIdx.x >> 1;                       // 0..767
        int b  = idx / (6 * PCHUNK);
        int ct = (idx / PCHUNK) % 6;
        int pc = idx % PCHUNK;
        int c0 = ct * 64;
        int h = lane >> 4;                               // 0..3
        int c = tid & 15, q = tid >> 4;                  // q in 0..15 (p-quad)
        const float* binb  = bins + (size_t)b * RHO_ * PIX_ + pc * 1024;
        const float* cartb = cart + ((size_t)b * C_ + c0) * PIX_ + pc * 1024;

        // per-lane global sources (source-swizzled X, linear W); per-wave LDS unit offsets
        const float* gX[4]; int uXo[4];
        #pragma unroll
        for (int k = 0; k < 4; ++k) {
            int u = w + 4 * k;                           // X unit 0..15, rows 4u..4u+3
            int row = 4 * u + h;
            gX[k] = cartb + (size_t)row * PIX_ + (((lane & 15) ^ (row & 15)) << 2);
            uXo[k] = u << 8;
        }
        const float* gW[2]; int uWo[2];
        #pragma unroll
        for (int k = 0; k < 2; ++k) {
            int u = w + 4 * k;                           // W unit 0..7 (rows 25..31 junk from pad)
            gW[k] = binb + (size_t)(4 * u + h) * PIX_ + ((lane & 15) << 2);
            uWo[k] = 4096 + (u << 8);
        }

        float acc[4][25];
        #pragma unroll
        for (int jj = 0; jj < 4; ++jj)
            #pragma unroll
            for (int r = 0; r < 25; ++r) acc[jj][r] = 0.f;

        // prologue: stage tile 0 into buffer 0 (6 loads/wave)
        #pragma unroll
        for (int k = 0; k < 4; ++k) gl_lds16(gX[k], smem + uXo[k]);
        #pragma unroll
        for (int k = 0; k < 2; ++k) gl_lds16(gW[k], smem + uWo[k]);

        for (int t = 0; t < 16; ++t) {
            int cbase = (t & 1) * BUF;
            int nbase = cbase ^ BUF;
            if (t < 15) {                                // stage t+1 (stays in flight past barrier)
                int p0 = (t + 1) << 6;
                #pragma unroll
                for (int k = 0; k < 4; ++k) gl_lds16(gX[k] + p0, smem + nbase + uXo[k]);
                #pragma unroll
                for (int k = 0; k < 2; ++k) gl_lds16(gW[k] + p0, smem + nbase + uWo[k]);
                asm volatile("s_waitcnt vmcnt(6)" ::: "memory");   // tile-t landed; 6 newer in flight
            } else {
                asm volatile("s_waitcnt vmcnt(0)" ::: "memory");
            }
            __builtin_amdgcn_sched_barrier(0);
            __builtin_amdgcn_s_barrier();
            const float* Xb = smem + cbase;
            const float* Wb = smem + cbase + 4096;
            int sx = (q ^ c) << 2;                       // un-swizzle on read (~2-way banks, free)
            float4 x0 = *(const float4*)(Xb + ((c     ) << 6) + sx);
            float4 x1 = *(const float4*)(Xb + ((c + 16) << 6) + sx);
            float4 x2 = *(const float4*)(Xb + ((c + 32) << 6) + sx);
            float4 x3 = *(const float4*)(Xb + ((c + 48) << 6) + sx);
            #pragma unroll
            for (int r = 0; r < 25; ++r) {
                float4 wv = *(const float4*)(Wb + (r << 6) + (q << 2));   // broadcast
                acc[0][r] += x0.x * wv.x + x0.y * wv.y + x0.z * wv.z + x0.w * wv.w;
                acc[1][r] += x1.x * wv.x + x1.y * wv.y + x1.z * wv.z + x1.w * wv.w;
                acc[2][r] += x2.x * wv.x + x2.y * wv.y + x2.z * wv.z + x2.w * wv.w;
                acc[3][r] += x3.x * wv.x + x3.y * wv.y + x3.z * wv.z + x3.w * wv.w;
            }
            __builtin_amdgcn_s_barrier();                // all reads of cbase done before restage
        }

        // fold h-groups within wave (q = 4w+h)
        #pragma unroll
        for (int jj = 0; jj < 4; ++jj)
            #pragma unroll
            for (int r = 0; r < 25; ++r) {
                acc[jj][r] += __shfl_xor(acc[jj][r], 16, 64);
                acc[jj][r] += __shfl_xor(acc[jj][r], 32, 64);
            }
        if (lane < 16) {                                 // h==0 lanes hold wave partials
            #pragma unroll
            for (int jj = 0; jj < 4; ++jj)
                #pragma unroll
                for (int r = 0; r < 25; ++r)
                    smem[((w * 4 + jj) * 16 + c) * 25 + r] = acc[jj][r];
        }
        __syncthreads();
        for (int oi = tid; oi < 1600; oi += 256) {
            int cc = oi / 25, r = oi % 25;
            int jj = cc >> 4, cl = cc & 15;
            float ssum = 0.f;
            #pragma unroll
            for (int ww = 0; ww < 4; ++ww)
                ssum += smem[((ww * 4 + jj) * 16 + cl) * 25 + r];
            atomicAdd(&fe[((size_t)(r * B_ + b)) * D_ + 384 + c0 + cc], ssum);
        }
    } else {
        // -------- polar role: width-mean, wave per row, ILP-4, 25 exact iterations --------
        int wid = (blockIdx.x >> 1) * 4 + w;             // 0..3071
        for (int it = 0; it < 25; ++it) {
            int r0 = wid + it * 4 * PNW;
            float s[4];
            #pragma unroll
            for (int k = 0; k < 4; ++k) {
                float4 v = ((const float4*)(polar + (size_t)(r0 + k * PNW) * WP_))[lane];
                s[k] = v.x + v.y + v.z + v.w;
            }
            #pragma unroll
            for (int m = 32; m >= 1; m >>= 1) {
                #pragma unroll
                for (int k = 0; k < 4; ++k) s[k] += __shfl_xor(s[k], m, 64);
            }
            if (lane == 0) {
                #pragma unroll
                for (int k = 0; k < 4; ++k) {
                    int r = r0 + k * PNW;
                    int rho = r % RHO_, cch = (r / RHO_) % C_, bb = r / (RHO_ * C_);
                    fe[((size_t)(rho * B_ + bb)) * D_ + cch] = s[k] * (1.f / 256.f);
                }
            }
        }
    }
}

// ---------------- K3: G[i][b][j] = fe[i][b][:] @ W1 + b1 ; wave per (i,b,j-half) ----------------
__global__ __launch_bounds__(256) void mlp_pre_kernel(const float* __restrict__ fe,
        const float* __restrict__ W1T, const float* __restrict__ b1_0,
        const float* __restrict__ b1s, float* __restrict__ G) {
    int lane = threadIdx.x & 63;
    int trip = blockIdx.x * 4 + (threadIdx.x >> 6);      // 0..1599 = (i,b,jh)
    int jh = trip & 1;
    int pair = trip >> 1;
    int i = pair >> 5, b = pair & 31;
    const float4* f4p = (const float4*)(fe + (size_t)(i * B_ + b) * D_);
    float4 f0 = f4p[lane], f1 = f4p[lane + 64], f2 = f4p[lane + 128];
    int j0 = jh * 20;
    #pragma unroll 2
    for (int j = j0; j < j0 + 20; ++j) {
        const float4* w4p = (const float4*)(W1T + ((size_t)i * HID_ + j) * D_);
        float4 w0 = w4p[lane], w1 = w4p[lane + 64], w2 = w4p[lane + 128];
        float s = f0.x*w0.x + f0.y*w0.y + f0.z*w0.z + f0.w*w0.w
                + f1.x*w1.x + f1.y*w1.y + f1.z*w1.z + f1.w*w1.w
                + f2.x*w2.x + f2.y*w2.y + f2.z*w2.z + f2.w*w2.w;
        #pragma unroll
        for (int m = 32; m >= 1; m >>= 1) s += __shfl_xor(s, m, 64);
        if (lane == 0) {
            float bias = (i == 0) ? b1_0[j] : b1s[(i - 1) * HID_ + j];
            G[(size_t)(i * B_ + b) * HID_ + j] = s + bias;
        }
    }
}

// ---------------- K4: sequential heads, register-resident, wave-synchronous ----------------
__global__ __launch_bounds__(64) void mlp_seq_kernel(const float* __restrict__ G,
        const float* __restrict__ W1s, const float* __restrict__ W2_0,
        const float* __restrict__ b2_0, const float* __restrict__ W2s,
        const float* __restrict__ b2s, float* __restrict__ out) {
    int lane = threadIdx.x;
    int j2 = lane & 31, b = blockIdx.x * 2 + (lane >> 5);
    bool hi = (j2 < 8);
    float g1[25], g2[25], wl1[25], wl2[25], w2a[25], w2b[25], bsc[25];
    #pragma unroll
    for (int i = 0; i < 25; ++i) {
        g1[i] = G[(size_t)(i * B_ + b) * HID_ + j2];
        g2[i] = hi ? G[(size_t)(i * B_ + b) * HID_ + 32 + j2] : 0.f;
    }
    wl1[0] = 0.f; wl2[0] = 0.f;
    w2a[0] = W2_0[j2]; w2b[0] = hi ? W2_0[32 + j2] : 0.f; bsc[0] = b2_0[0];
    #pragma unroll
    for (int i = 1; i < 25; ++i) {
        size_t base = ((size_t)(i - 1) * 769 + 768) * HID_;   // recurrent row of W1
        wl1[i] = W1s[base + j2];
        wl2[i] = hi ? W1s[base + 32 + j2] : 0.f;
        w2a[i] = W2s[(i - 1) * HID_ + j2];
        w2b[i] = hi ? W2s[(i - 1) * HID_ + 32 + j2] : 0.f;
        bsc[i] = b2s[i - 1];
    }
    float op = 0.f;
    #pragma unroll
    for (int i = 0; i < 25; ++i) {
        float x1 = g1[i] + op * wl1[i];
        float x2 = g2[i] + op * wl2[i];
        float p = gelu_exact(x1) * w2a[i] + gelu_exact(x2) * w2b[i];
        #pragma unroll
        for (int m = 16; m >= 1; m >>= 1) p += __shfl_xor(p, m, 64);   // stays within 32-lane group
        float o = p + bsc[i];
        op = o;
        if (j2 == 0) out[b * 25 + i] = fminf(fmaxf(o, 0.f), 3.14159265358979323846f);
    }
}

extern "C" void kernel_launch(void* const* d_in, const int* in_sizes, int n_in,
                              void* d_out, int out_size, void* d_ws, size_t ws_size,
                              hipStream_t stream) {
    const float* polar = (const float*)d_in[0];
    const float* cart  = (const float*)d_in[1];
    const float* grid  = (const float*)d_in[2];
    const float* W1_0  = (const float*)d_in[3];
    const float* b1_0  = (const float*)d_in[4];
    const float* W2_0  = (const float*)d_in[5];
    const float* b2_0  = (const float*)d_in[6];
    const float* W1s   = (const float*)d_in[7];
    const float* b1s   = (const float*)d_in[8];
    const float* W2s   = (const float*)d_in[9];
    const float* b2s   = (const float*)d_in[10];
    float* out = (float*)d_out;

    // ws layout (floats): bins[800*4096 + 8*4096 pad (junk W rows 25..31)] | fe | G | W1T
    float* bins = (float*)d_ws;
    float* fe   = bins + (size_t)(B_ * RHO_ + 8) * PIX_;
    float* G    = fe + (size_t)FE_N;
    float* W1T  = G + (size_t)RHO_ * B_ * HID_;

    prep_kernel<<<B_ * RHO_ + 25 + 50, 256, 0, stream>>>(grid, W1_0, W1s, bins, W1T, fe);
    main_kernel<<<MAINBLK, 256, 0, stream>>>(polar, cart, bins, fe);
    mlp_pre_kernel<<<(RHO_ * B_ * 2) / 4, 256, 0, stream>>>(fe, W1T, b1_0, b1s, G);
    mlp_seq_kernel<<<B_ / 2, 64, 0, stream>>>(G, W1s, W2_0, b2_0, W2s, b2s, out);
}